// Round 1
// baseline (324.459 us; speedup 1.0000x reference)
//
#include <hip/hip_runtime.h>
#include <math.h>

namespace {

constexpr int Bc = 16, Nc = 1024, Ec = 128, Hc = 8, KDc = 16, HKc = 128;
constexpr int ROWS = 16;          // rows per block in qkv kernel
constexpr int QT = 32, MT = 64;   // q-tile rows per block, m-tile (key) rows per LDS stage

// ---------------- Kernel 1: fused Q,K,V projection ----------------
// grid = B*N/ROWS blocks x 256 threads. Output layout [B][N][H*KD] (row-major,
// all heads contiguous per token) so attention staging loads are coalesced.
__global__ __launch_bounds__(256) void qkv_kernel(
    const float* __restrict__ hin,
    const float* __restrict__ Wq,
    const float* __restrict__ Wk,
    const float* __restrict__ Wv,
    float* __restrict__ Q, float* __restrict__ K, float* __restrict__ V)
{
  __shared__ float h_lds[ROWS][Ec];
  const int t = threadIdx.x;
  const int row0 = blockIdx.x * ROWS;

  // stage 16 token rows of h (coalesced float4)
  const float4* hsrc = reinterpret_cast<const float4*>(hin + (size_t)row0 * Ec);
  float4* hdst = reinterpret_cast<float4*>(&h_lds[0][0]);
  hdst[t]        = hsrc[t];
  hdst[t + 256]  = hsrc[t + 256];
  __syncthreads();

  const int c  = t & 127;   // output column = head*16 + k
  const int rg = t >> 7;    // row group 0/1 (8 rows each)
  const int head = c >> 4, kk = c & 15;
  const float* wq = Wq + head * (Ec * KDc) + kk;
  const float* wk = Wk + head * (Ec * KDc) + kk;
  const float* wv = Wv + head * (Ec * KDc) + kk;

  float aq[8], ak[8], av[8];
  #pragma unroll
  for (int r = 0; r < 8; ++r) { aq[r] = 0.f; ak[r] = 0.f; av[r] = 0.f; }

  #pragma unroll 4
  for (int e = 0; e < Ec; ++e) {
    const float q_ = wq[e * KDc];
    const float k_ = wk[e * KDc];
    const float v_ = wv[e * KDc];
    #pragma unroll
    for (int r = 0; r < 8; ++r) {
      const float hv = h_lds[rg * 8 + r][e];   // LDS broadcast within wave
      aq[r] = fmaf(hv, q_, aq[r]);
      ak[r] = fmaf(hv, k_, ak[r]);
      av[r] = fmaf(hv, v_, av[r]);
    }
  }

  #pragma unroll
  for (int r = 0; r < 8; ++r) {
    const size_t row = (size_t)row0 + rg * 8 + r;
    Q[row * HKc + c] = aq[r];
    K[row * HKc + c] = ak[r];
    V[row * HKc + c] = av[r];
  }
}

// ---------------- Kernel 2: masked flash attention + output proj ----------------
// grid = B * (N/QT) blocks x 256 threads. thread = (head = t>>5, q = t&31):
// all 8 heads of a q-row tile live in one block -> adj tile read ONCE for all heads.
// Online softmax is fully thread-local (KD=16 accumulators in registers).
__global__ __launch_bounds__(256) void attn_kernel(
    const float* __restrict__ Q,
    const float* __restrict__ Kw,
    const float* __restrict__ Vw,
    const int*   __restrict__ adj,
    const float* __restrict__ hin,
    const float* __restrict__ Wout,
    float* __restrict__ out)
{
  __shared__ float K_lds[MT][HKc];                 // 32 KB (reused as heads buffer)
  __shared__ float V_lds[MT][HKc];                 // 32 KB
  __shared__ unsigned char adj_u8[QT][MT + 4];     // pad 68 -> conflict-free reads

  const int t  = threadIdx.x;
  const int b  = blockIdx.x >> 5;            // N/QT = 32 tiles per batch
  const int qb = (blockIdx.x & 31) * QT;
  const int h8 = t >> 5;                     // head
  const int q  = t & 31;                     // local q row
  const size_t grow = (size_t)b * Nc + qb + q;

  // Q fragment, pre-scaled by 1/sqrt(16)
  float Qr[16];
  {
    const float4* qs = reinterpret_cast<const float4*>(Q + grow * HKc + h8 * KDc);
    #pragma unroll
    for (int j = 0; j < 4; ++j) {
      const float4 v = qs[j];
      Qr[j*4+0] = v.x * 0.25f; Qr[j*4+1] = v.y * 0.25f;
      Qr[j*4+2] = v.z * 0.25f; Qr[j*4+3] = v.w * 0.25f;
    }
  }

  float M = -INFINITY, S = 0.f;
  float acc[16];
  #pragma unroll
  for (int k = 0; k < 16; ++k) acc[k] = 0.f;

  for (int mt = 0; mt < Nc / MT; ++mt) {
    __syncthreads();
    // stage K,V tiles (coalesced float4)
    const float4* ks = reinterpret_cast<const float4*>(Kw + ((size_t)b * Nc + mt * MT) * HKc);
    const float4* vs = reinterpret_cast<const float4*>(Vw + ((size_t)b * Nc + mt * MT) * HKc);
    float4* kd = reinterpret_cast<float4*>(&K_lds[0][0]);
    float4* vd = reinterpret_cast<float4*>(&V_lds[0][0]);
    #pragma unroll
    for (int i = 0; i < (MT * HKc / 4) / 256; ++i) {   // 8
      kd[t + i * 256] = ks[t + i * 256];
      vd[t + i * 256] = vs[t + i * 256];
    }
    // stage adjacency tile once for all 8 heads
    const int* as = adj + (size_t)b * Nc * Nc + (size_t)qb * Nc + mt * MT;
    #pragma unroll
    for (int i = 0; i < (QT * MT) / 256; ++i) {        // 8
      const int idx = t + i * 256;
      const int qq = idx >> 6;
      const int mm = idx & 63;
      adj_u8[qq][mm] = (unsigned char)as[(size_t)qq * Nc + mm];
    }
    __syncthreads();

    #pragma unroll 2
    for (int m = 0; m < MT; ++m) {
      // K row: half-wave-uniform address -> LDS broadcast, conflict-free
      const float4* krow = reinterpret_cast<const float4*>(&K_lds[m][h8 * KDc]);
      const float4 k0 = krow[0], k1 = krow[1], k2 = krow[2], k3 = krow[3];
      float s;
      s = Qr[0] * k0.x;
      s = fmaf(Qr[1],  k0.y, s); s = fmaf(Qr[2],  k0.z, s); s = fmaf(Qr[3],  k0.w, s);
      s = fmaf(Qr[4],  k1.x, s); s = fmaf(Qr[5],  k1.y, s); s = fmaf(Qr[6],  k1.z, s);
      s = fmaf(Qr[7],  k1.w, s); s = fmaf(Qr[8],  k2.x, s); s = fmaf(Qr[9],  k2.y, s);
      s = fmaf(Qr[10], k2.z, s); s = fmaf(Qr[11], k2.w, s); s = fmaf(Qr[12], k3.x, s);
      s = fmaf(Qr[13], k3.y, s); s = fmaf(Qr[14], k3.z, s); s = fmaf(Qr[15], k3.w, s);

      if (adj_u8[q][m]) {
        if (s > M) {                       // rare after warmup
          const float cs = __expf(M - s);  // M=-inf first time -> 0, correct reset
          S *= cs;
          #pragma unroll
          for (int k = 0; k < 16; ++k) acc[k] *= cs;
          M = s;
        }
        const float p = __expf(s - M);
        S += p;
        const float4* vrow = reinterpret_cast<const float4*>(&V_lds[m][h8 * KDc]);
        const float4 v0 = vrow[0], v1 = vrow[1], v2 = vrow[2], v3 = vrow[3];
        acc[0]  = fmaf(p, v0.x, acc[0]);  acc[1]  = fmaf(p, v0.y, acc[1]);
        acc[2]  = fmaf(p, v0.z, acc[2]);  acc[3]  = fmaf(p, v0.w, acc[3]);
        acc[4]  = fmaf(p, v1.x, acc[4]);  acc[5]  = fmaf(p, v1.y, acc[5]);
        acc[6]  = fmaf(p, v1.z, acc[6]);  acc[7]  = fmaf(p, v1.w, acc[7]);
        acc[8]  = fmaf(p, v2.x, acc[8]);  acc[9]  = fmaf(p, v2.y, acc[9]);
        acc[10] = fmaf(p, v2.z, acc[10]); acc[11] = fmaf(p, v2.w, acc[11]);
        acc[12] = fmaf(p, v3.x, acc[12]); acc[13] = fmaf(p, v3.y, acc[13]);
        acc[14] = fmaf(p, v3.z, acc[14]); acc[15] = fmaf(p, v3.w, acc[15]);
      }
    }
  }

  // normalize, park heads in (reused) K_lds: [QT][132] padded, conflict-free
  const float inv = 1.0f / S;   // self-loop guarantees S >= 1
  __syncthreads();
  float* heads = reinterpret_cast<float*>(&K_lds[0][0]);
  #pragma unroll
  for (int k = 0; k < 16; ++k) heads[q * 132 + h8 * KDc + k] = acc[k] * inv;
  __syncthreads();

  // output projection + residual: thread = (q2 = t>>3, e-group = t&7)
  const int q2 = t >> 3, eg = t & 7;
  const size_t orow = (size_t)b * Nc + qb + q2;
  const float4* res = reinterpret_cast<const float4*>(hin + orow * Ec + eg * 16);
  float4 o0 = res[0], o1 = res[1], o2 = res[2], o3 = res[3];
  for (int hk = 0; hk < HKc; ++hk) {
    const float hv = heads[q2 * 132 + hk];          // 8-way broadcast, distinct banks
    const float4* w4 = reinterpret_cast<const float4*>(Wout + hk * Ec + eg * 16);
    const float4 wa = w4[0], wb = w4[1], wc = w4[2], wd = w4[3];
    o0.x = fmaf(hv, wa.x, o0.x); o0.y = fmaf(hv, wa.y, o0.y);
    o0.z = fmaf(hv, wa.z, o0.z); o0.w = fmaf(hv, wa.w, o0.w);
    o1.x = fmaf(hv, wb.x, o1.x); o1.y = fmaf(hv, wb.y, o1.y);
    o1.z = fmaf(hv, wb.z, o1.z); o1.w = fmaf(hv, wb.w, o1.w);
    o2.x = fmaf(hv, wc.x, o2.x); o2.y = fmaf(hv, wc.y, o2.y);
    o2.z = fmaf(hv, wc.z, o2.z); o2.w = fmaf(hv, wc.w, o2.w);
    o3.x = fmaf(hv, wd.x, o3.x); o3.y = fmaf(hv, wd.y, o3.y);
    o3.z = fmaf(hv, wd.z, o3.z); o3.w = fmaf(hv, wd.w, o3.w);
  }
  float4* od = reinterpret_cast<float4*>(out + orow * Ec + eg * 16);
  od[0] = o0; od[1] = o1; od[2] = o2; od[3] = o3;
}

} // namespace

extern "C" void kernel_launch(void* const* d_in, const int* in_sizes, int n_in,
                              void* d_out, int out_size, void* d_ws, size_t ws_size,
                              hipStream_t stream) {
  (void)in_sizes; (void)n_in; (void)out_size; (void)ws_size;
  const float* h   = (const float*)d_in[0];
  const int*   adj = (const int*)d_in[1];
  const float* Wq  = (const float*)d_in[2];
  const float* Wk  = (const float*)d_in[3];
  const float* Wv  = (const float*)d_in[4];
  const float* Wo  = (const float*)d_in[5];
  float* out = (float*)d_out;

  // workspace: Q,K,V in [B][N][H*KD] fp32 -> 3 x 8 MB = 24 MB
  float* Qw = (float*)d_ws;
  float* Kw = Qw + (size_t)Bc * Nc * HKc;
  float* Vw = Kw + (size_t)Bc * Nc * HKc;

  qkv_kernel<<<Bc * Nc / ROWS, 256, 0, stream>>>(h, Wq, Wk, Wv, Qw, Kw, Vw);
  attn_kernel<<<Bc * (Nc / QT), 256, 0, stream>>>(Qw, Kw, Vw, adj, h, Wo, out);
}

// Round 2
// 111.313 us; speedup vs baseline: 2.9148x; 2.9148x over previous
//
#include <hip/hip_runtime.h>
#include <hip/hip_bf16.h>
#include <math.h>
#include <stdint.h>

namespace {

constexpr int Bc = 16, Nc = 1024, Ec = 128, Hc = 8, KDc = 16, HKc = 128;
// 1/sqrt(KD) * log2(e): fold softmax scale + base-2 conversion into Q
constexpr float SCALE = 0.25f * 1.4426950408889634f;

typedef __attribute__((ext_vector_type(8))) short short8;
typedef __attribute__((ext_vector_type(16))) float f32x16;

__device__ inline uint16_t f2bf(float f) {
  __hip_bfloat16 h = __float2bfloat16(f);
  uint16_t s; __builtin_memcpy(&s, &h, 2);
  return s;
}

// ---------------- Kernel 1: fused Q,K,V projection -> bf16 MFMA-fragment layouts ----
// Q/K frag layout [b][h][blk32][lane64][elem8]:
//   lane = (n&31) + 32*((kd>>2)&1), elem = (kd&3) + 4*(kd>>3)
//   (A-operand rows = keys = n&31 for K; B-operand cols = q = n&31 for Q; same formula)
// V frag layout [b][h][mblk32][half2][lid32][elem8]:
//   B-operand for PV: col = kd, k-rows = key&15 per 16-key half
__global__ __launch_bounds__(256) void qkv_kernel(
    const float* __restrict__ hin,
    const float* __restrict__ Wq, const float* __restrict__ Wk, const float* __restrict__ Wv,
    uint16_t* __restrict__ Qf, uint16_t* __restrict__ Kf, uint16_t* __restrict__ Vf)
{
  __shared__ float h_lds[16][Ec];
  const int t = threadIdx.x;
  const int row0 = blockIdx.x * 16;

  const float4* hsrc = reinterpret_cast<const float4*>(hin + (size_t)row0 * Ec);
  float4* hdst = reinterpret_cast<float4*>(&h_lds[0][0]);
  hdst[t] = hsrc[t]; hdst[t + 256] = hsrc[t + 256];
  __syncthreads();

  const int c = t & 127, rg = t >> 7;
  const int head = c >> 4, kd = c & 15;
  const float* wq = Wq + head * (Ec * KDc) + kd;
  const float* wk = Wk + head * (Ec * KDc) + kd;
  const float* wv = Wv + head * (Ec * KDc) + kd;

  float aq[8], ak[8], av[8];
  #pragma unroll
  for (int r = 0; r < 8; ++r) { aq[r] = 0.f; ak[r] = 0.f; av[r] = 0.f; }

  #pragma unroll 4
  for (int e = 0; e < Ec; ++e) {
    const float q_ = wq[e * KDc];
    const float k_ = wk[e * KDc];
    const float v_ = wv[e * KDc];
    #pragma unroll
    for (int r = 0; r < 8; ++r) {
      const float hv = h_lds[rg * 8 + r][e];
      aq[r] = fmaf(hv, q_, aq[r]);
      ak[r] = fmaf(hv, k_, ak[r]);
      av[r] = fmaf(hv, v_, av[r]);
    }
  }

  const int b = row0 >> 10;
  const int h5 = (kd >> 2) & 1;
  const int elem = (kd & 3) + 4 * (kd >> 3);

  #pragma unroll
  for (int r = 0; r < 8; ++r) {
    const int n = (row0 & 1023) + rg * 8 + r;
    const int blk = n >> 5;
    const int lane = (n & 31) + 32 * h5;
    const size_t qkoff = ((((size_t)b * Hc + head) * 32 + blk) * 64 + lane) * 8 + elem;
    Qf[qkoff] = f2bf(aq[r] * SCALE);
    Kf[qkoff] = f2bf(ak[r]);
    const int half = (n >> 4) & 1, krow = n & 15;
    const int h5v = (krow >> 2) & 1;
    const int iv = (krow & 3) + 4 * (krow >> 3);
    const int lid = kd + 16 * h5v;
    const size_t voff = (((((size_t)b * Hc + head) * 32 + blk) * 2 + half) * 32 + lid) * 8 + iv;
    Vf[voff] = f2bf(av[r]);
  }
}

// ---------------- Kernel 2: MFMA masked flash attention + out-proj ----------------
// 512 threads = 8 waves, wave w = head w; block = (b, 32 q-rows).
// Swapped QK^T: D[key][q] = K·Q^T so softmax is per-lane (col q = lane&31).
// D-regs feed PV A-operand directly (slot order matches by construction).
__global__ __launch_bounds__(512, 4) void attn_kernel(
    const uint16_t* __restrict__ Qf, const uint16_t* __restrict__ Kf,
    const uint16_t* __restrict__ Vf, const int* __restrict__ adj,
    const float* __restrict__ hin, const float* __restrict__ Wout,
    float* __restrict__ out)
{
  __shared__ uint32_t adj_bits[32][33];   // [q-row][word]; word w covers keys 32w..32w+31
  __shared__ float heads[32][132];        // [q-row][h*16+kd], padded

  const int t = threadIdx.x;
  const int b = blockIdx.x >> 5;
  const int qblk = blockIdx.x & 31;
  const int w = t >> 6;       // head
  const int l = t & 63;
  const int h5 = l >> 5;
  const int q = l & 31;
  const int rowbase = h5 * 4;

  // ---- stage adjacency bitmasks: wave w packs q-rows w*4 .. w*4+3 via ballot ----
  {
    const int r0 = w * 4;
    const size_t arow0 = (size_t)(b * Nc + qblk * 32 + r0) * Nc;
    for (int cch = 0; cch < 16; ++cch) {
      int vv[4];
      #pragma unroll
      for (int j = 0; j < 4; ++j)
        vv[j] = adj[arow0 + (size_t)j * Nc + cch * 64 + l];
      #pragma unroll
      for (int j = 0; j < 4; ++j) {
        const unsigned long long m = __ballot(vv[j] != 0);
        if (l == 0) {
          adj_bits[r0 + j][2 * cch]     = (uint32_t)m;
          adj_bits[r0 + j][2 * cch + 1] = (uint32_t)(m >> 32);
        }
      }
    }
  }

  // Q fragment (B-operand), loaded once
  const short8 qfrag = *reinterpret_cast<const short8*>(
      Qf + ((((size_t)b * Hc + w) * 32 + qblk) * 64 + l) * 8);

  __syncthreads();

  f32x16 acc, zc;
  #pragma unroll
  for (int i = 0; i < 16; ++i) { acc[i] = 0.f; zc[i] = 0.f; }
  float M = -1e29f, S = 0.f;

  const uint16_t* kbase = Kf + (((size_t)b * Hc + w) * 32) * 512 + (size_t)l * 8;
  const uint16_t* vbase = Vf + (((size_t)b * Hc + w) * 32) * 512 + (size_t)(q + 16 * h5) * 8;

  for (int mblk = 0; mblk < 32; ++mblk) {
    const short8 kfrag = *reinterpret_cast<const short8*>(kbase + (size_t)mblk * 512);
    f32x16 s = __builtin_amdgcn_mfma_f32_32x32x16_bf16(kfrag, qfrag, zc, 0, 0, 0);

    const uint32_t word = adj_bits[q][mblk];
    const uint32_t wsh = word >> (4 * h5);   // bit r = (r&3)+8*(r>>2) after shift
    float sm[16];
    #pragma unroll
    for (int r = 0; r < 16; ++r) {
      const uint32_t msk = 1u << ((r & 3) + 8 * (r >> 2));
      sm[r] = (wsh & msk) ? s[r] : -1e30f;
    }

    float pm = fmaxf(fmaxf(fmaxf(sm[0], sm[1]), fmaxf(sm[2], sm[3])),
                     fmaxf(fmaxf(sm[4], sm[5]), fmaxf(sm[6], sm[7])));
    pm = fmaxf(pm, fmaxf(fmaxf(fmaxf(sm[8], sm[9]), fmaxf(sm[10], sm[11])),
                         fmaxf(fmaxf(sm[12], sm[13]), fmaxf(sm[14], sm[15]))));
    pm = fmaxf(pm, __shfl_xor(pm, 32));

    if (__any(pm > M + 8.f)) {            // defer-max (T13): rescale rarely
      const float nM = fmaxf(M, pm);
      const float cs = __builtin_amdgcn_exp2f(M - nM);
      S *= cs; M = nM;
      #pragma unroll
      for (int r = 0; r < 16; ++r)
        acc[r] *= __shfl(cs, (r & 3) + 8 * (r >> 2) + rowbase);
    }

    float p[16];
    #pragma unroll
    for (int r = 0; r < 16; ++r) p[r] = __builtin_amdgcn_exp2f(sm[r] - M);
    S += (((p[0] + p[1]) + (p[2] + p[3])) + ((p[4] + p[5]) + (p[6] + p[7])))
       + (((p[8] + p[9]) + (p[10] + p[11])) + ((p[12] + p[13]) + (p[14] + p[15])));

    short8 pa0, pa1;
    #pragma unroll
    for (int i = 0; i < 8; ++i) { pa0[i] = (short)f2bf(p[i]); pa1[i] = (short)f2bf(p[i + 8]); }

    short8 v0, v1;
    if (q < 16) {
      const uint16_t* vp = vbase + (size_t)mblk * 512;
      v0 = *reinterpret_cast<const short8*>(vp);
      v1 = *reinterpret_cast<const short8*>(vp + 256);
    } else {
      #pragma unroll
      for (int i = 0; i < 8; ++i) { v0[i] = 0; v1[i] = 0; }
    }
    acc = __builtin_amdgcn_mfma_f32_32x32x16_bf16(pa0, v0, acc, 0, 0, 0);
    acc = __builtin_amdgcn_mfma_f32_32x32x16_bf16(pa1, v1, acc, 0, 0, 0);
  }

  // ---- finalize: combine half-sums, normalize, park in LDS ----
  S += __shfl_xor(S, 32);
  const float inv = 1.0f / S;
  float o[16];
  #pragma unroll
  for (int r = 0; r < 16; ++r)
    o[r] = acc[r] * __shfl(inv, (r & 3) + 8 * (r >> 2) + rowbase);
  if (q < 16) {
    #pragma unroll
    for (int r = 0; r < 16; ++r)
      heads[(r & 3) + 8 * (r >> 2) + rowbase][w * 16 + q] = o[r];
  }
  __syncthreads();

  // ---- output projection + residual: thread = (q2 = t>>4, eg = t&15 -> 8 e-cols) ----
  const int q2 = t >> 4, eg = t & 15;
  const size_t orow = (size_t)(b * Nc + qblk * 32 + q2);
  const float4* res = reinterpret_cast<const float4*>(hin + orow * Ec + eg * 8);
  float4 o0 = res[0], o1 = res[1];
  for (int hk = 0; hk < HKc; ++hk) {
    const float hv = heads[q2][hk];                       // 16-lane broadcast
    const float4* w4 = reinterpret_cast<const float4*>(Wout + (size_t)hk * Ec + eg * 8);
    const float4 wa = w4[0], wb = w4[1];
    o0.x = fmaf(hv, wa.x, o0.x); o0.y = fmaf(hv, wa.y, o0.y);
    o0.z = fmaf(hv, wa.z, o0.z); o0.w = fmaf(hv, wa.w, o0.w);
    o1.x = fmaf(hv, wb.x, o1.x); o1.y = fmaf(hv, wb.y, o1.y);
    o1.z = fmaf(hv, wb.z, o1.z); o1.w = fmaf(hv, wb.w, o1.w);
  }
  float4* od = reinterpret_cast<float4*>(out + orow * Ec + eg * 8);
  od[0] = o0; od[1] = o1;
}

} // namespace

extern "C" void kernel_launch(void* const* d_in, const int* in_sizes, int n_in,
                              void* d_out, int out_size, void* d_ws, size_t ws_size,
                              hipStream_t stream) {
  (void)in_sizes; (void)n_in; (void)out_size; (void)ws_size;
  const float* h   = (const float*)d_in[0];
  const int*   adj = (const int*)d_in[1];
  const float* Wq  = (const float*)d_in[2];
  const float* Wk  = (const float*)d_in[3];
  const float* Wv  = (const float*)d_in[4];
  const float* Wo  = (const float*)d_in[5];
  float* out = (float*)d_out;

  // workspace: Qf/Kf/Vf bf16 fragment buffers, 4 MB each
  uint16_t* Qf = (uint16_t*)d_ws;
  uint16_t* Kf = Qf + (size_t)Bc * Hc * Nc * KDc;
  uint16_t* Vf = Kf + (size_t)Bc * Hc * Nc * KDc;

  qkv_kernel<<<Bc * Nc / 16, 256, 0, stream>>>(h, Wq, Wk, Wv, Qf, Kf, Vf);
  attn_kernel<<<Bc * (Nc / 32), 512, 0, stream>>>(Qf, Kf, Vf, adj, h, Wo, out);
}